// Round 1
// baseline (163.653 us; speedup 1.0000x reference)
//
#include <hip/hip_runtime.h>
#include <math.h>

// Problem dims (fixed by the reference)
#define B_DIM   128
#define C_DIM   512
#define HW      784      // 28*28
#define HW4     196      // HW/4 float4s per (b,c) row
#define NCLS    1000
#define MBINS   50
#define NROWS   (B_DIM * C_DIM)   // 65536
#define ALPHA   100.0f

__device__ __forceinline__ float wave_reduce_sum(float v) {
    #pragma unroll
    for (int off = 32; off > 0; off >>= 1) v += __shfl_xor(v, off, 64);
    return v;
}

// ---------------- Kernel 1: spatial sum pool: pooled[b,c] = sum_hw act ------
// One 64-lane wave per (b,c) row; 196 float4 per row = 3 full strides + 4.
__global__ void pool_kernel(const float* __restrict__ act,
                            float* __restrict__ pooled) {
    int gid  = blockIdx.x * blockDim.x + threadIdx.x;
    int row  = gid >> 6;
    int lane = gid & 63;
    if (row >= NROWS) return;
    const float4* p = reinterpret_cast<const float4*>(act) + (size_t)row * HW4;
    float s = 0.f;
    #pragma unroll
    for (int i = 0; i < 3; ++i) {
        float4 v = p[lane + i * 64];
        s += (v.x + v.y) + (v.z + v.w);
    }
    if (lane < 4) {
        float4 v = p[192 + lane];
        s += (v.x + v.y) + (v.z + v.w);
    }
    s = wave_reduce_sum(s);
    if (lane == 0) pooled[row] = s;
}

// ---------------- Kernel 2: logits[b,n] = (1/784) * sum_c pooled[b,c]*W[c,n]
// grid (4, B); block 256 threads; pooled row staged in LDS (broadcast reads).
__global__ void logits_kernel(const float* __restrict__ pooled,
                              const float* __restrict__ W,
                              float* __restrict__ logits) {
    __shared__ float sp[C_DIM];
    int b = blockIdx.y;
    for (int c = threadIdx.x; c < C_DIM; c += 256) sp[c] = pooled[b * C_DIM + c];
    __syncthreads();
    int n = blockIdx.x * 256 + threadIdx.x;
    if (n >= NCLS) return;
    float acc = 0.f;
    #pragma unroll 4
    for (int c = 0; c < C_DIM; ++c) acc += sp[c] * W[c * NCLS + n];
    logits[b * NCLS + n] = acc * (1.0f / (float)HW);
}

// ---------------- Kernel 3: in-place softmax -> q = p - 1/N ----------------
__global__ void softmax_kernel(float* __restrict__ logits) {
    int b = blockIdx.x;
    float* row = logits + b * NCLS;
    int tid = threadIdx.x, wid = tid >> 6, lane = tid & 63;
    __shared__ float red[4];

    float v[4];
    int cnt = 0;
    float m = -1e30f;
    for (int i = tid; i < NCLS; i += 256) { float x = row[i]; v[cnt++] = x; m = fmaxf(m, x); }
    #pragma unroll
    for (int off = 32; off > 0; off >>= 1) m = fmaxf(m, __shfl_xor(m, off, 64));
    if (lane == 0) red[wid] = m;
    __syncthreads();
    float mm = fmaxf(fmaxf(red[0], red[1]), fmaxf(red[2], red[3]));
    __syncthreads();   // everyone done reading red before reuse

    float s = 0.f;
    for (int k = 0; k < cnt; ++k) { v[k] = expf(v[k] - mm); s += v[k]; }
    s = wave_reduce_sum(s);
    if (lane == 0) red[wid] = s;
    __syncthreads();
    float tot = (red[0] + red[1]) + (red[2] + red[3]);
    float inv = 1.0f / tot;

    cnt = 0;
    for (int i = tid; i < NCLS; i += 256)
        row[i] = v[cnt++] * inv - (1.0f / (float)NCLS);
}

// ---------------- Kernel 4: gA[b,c] = (ALPHA/784) * sum_n q[b,n]*W[c,n] ----
// grid (2, B); q row in LDS (broadcast); each thread streams one W row (L2-hot).
__global__ void gcalc_kernel(const float* __restrict__ q,
                             const float* __restrict__ W,
                             float* __restrict__ gA) {
    __shared__ float sq[NCLS];
    int b = blockIdx.y;
    for (int i = threadIdx.x; i < NCLS; i += 256) sq[i] = q[b * NCLS + i];
    __syncthreads();
    int c = blockIdx.x * 256 + threadIdx.x;
    const float4* wr = reinterpret_cast<const float4*>(W + c * NCLS);
    float acc = 0.f;
    #pragma unroll 5
    for (int n = 0; n < NCLS / 4; ++n) {
        float4 wv = wr[n];
        acc += sq[4*n] * wv.x + sq[4*n+1] * wv.y + sq[4*n+2] * wv.z + sq[4*n+3] * wv.w;
    }
    gA[b * C_DIM + c] = acc * (ALPHA / (float)HW);
}

// ---------------- Kernel 5: states -> histogram ----------------------------
// One wave per (b,c): mean_hw sigmoid(gA * act), bin, atomicAdd to hist[c][bin].
__global__ void hist_kernel(const float* __restrict__ act,
                            const float* __restrict__ gA,
                            float* __restrict__ hist) {
    int gid  = blockIdx.x * blockDim.x + threadIdx.x;
    int row  = gid >> 6;
    int lane = gid & 63;
    if (row >= NROWS) return;
    float g = gA[row];
    const float4* p = reinterpret_cast<const float4*>(act) + (size_t)row * HW4;
    float s = 0.f;
    #pragma unroll
    for (int i = 0; i < 3; ++i) {
        float4 v = p[lane + i * 64];
        s += 1.0f / (1.0f + expf(-g * v.x));
        s += 1.0f / (1.0f + expf(-g * v.y));
        s += 1.0f / (1.0f + expf(-g * v.z));
        s += 1.0f / (1.0f + expf(-g * v.w));
    }
    if (lane < 4) {
        float4 v = p[192 + lane];
        s += 1.0f / (1.0f + expf(-g * v.x));
        s += 1.0f / (1.0f + expf(-g * v.y));
        s += 1.0f / (1.0f + expf(-g * v.z));
        s += 1.0f / (1.0f + expf(-g * v.w));
    }
    s = wave_reduce_sum(s);
    if (lane == 0) {
        float st = s * (1.0f / (float)HW);
        int idx = (int)floorf(st * (float)MBINS);
        idx = idx < 0 ? 0 : (idx > MBINS - 1 ? MBINS - 1 : idx);
        int c = row & (C_DIM - 1);
        atomicAdd(hist + c * MBINS + idx, 1.0f);
    }
}

extern "C" void kernel_launch(void* const* d_in, const int* in_sizes, int n_in,
                              void* d_out, int out_size, void* d_ws, size_t ws_size,
                              hipStream_t stream) {
    const float* act = (const float*)d_in[0];   // (B,C,H,W) fp32
    const float* W   = (const float*)d_in[1];   // (C,N) fp32
    float* hist      = (float*)d_out;           // (C, MBINS) fp32

    char* ws = (char*)d_ws;
    float* pooled = (float*)ws;                                   // 65536 f
    float* logits = (float*)(ws + (size_t)NROWS * 4);             // 128000 f (reused as q)
    float* gA     = (float*)(ws + (size_t)NROWS * 4
                                + (size_t)B_DIM * NCLS * 4);      // 65536 f

    // Output must be zeroed every call (harness poisons once, never restores).
    hipMemsetAsync(d_out, 0, (size_t)C_DIM * MBINS * sizeof(float), stream);

    pool_kernel   <<<NROWS / 4, 256, 0, stream>>>(act, pooled);
    logits_kernel <<<dim3(4, B_DIM), 256, 0, stream>>>(pooled, W, logits);
    softmax_kernel<<<B_DIM, 256, 0, stream>>>(logits);
    gcalc_kernel  <<<dim3(2, B_DIM), 256, 0, stream>>>(logits, W, gA);
    hist_kernel   <<<NROWS / 4, 256, 0, stream>>>(act, gA, hist);
}

// Round 2
// 155.641 us; speedup vs baseline: 1.0515x; 1.0515x over previous
//
#include <hip/hip_runtime.h>
#include <math.h>

// Problem dims (fixed by the reference)
#define B_DIM   128
#define C_DIM   512
#define HW      784      // 28*28
#define HW4     196      // HW/4 float4s per (b,c) row
#define NCLS    1000
#define MBINS   50
#define NROWS   (B_DIM * C_DIM)   // 65536
#define ALPHA   100.0f
#define OUT_ELTS (C_DIM * MBINS)  // 25600 floats

__device__ __forceinline__ float wave_reduce_sum(float v) {
    #pragma unroll
    for (int off = 32; off > 0; off >>= 1) v += __shfl_xor(v, off, 64);
    return v;
}

// ---------------- Kernel 1: spatial sum pool + d_out zeroing ---------------
// One 64-lane wave per (b,c) row; 196 float4 per row = 3 full strides + 4.
// First 100 blocks also zero the 25600-float output histogram (stream-ordered
// before hist_kernel's atomics; replaces the pathologically slow fill node).
__global__ void pool_kernel(const float* __restrict__ act,
                            float* __restrict__ pooled,
                            float* __restrict__ hist_out) {
    if (blockIdx.x < OUT_ELTS / 256) {
        hist_out[blockIdx.x * 256 + threadIdx.x] = 0.0f;
    }
    int gid  = blockIdx.x * blockDim.x + threadIdx.x;
    int row  = gid >> 6;
    int lane = gid & 63;
    if (row >= NROWS) return;
    const float4* p = reinterpret_cast<const float4*>(act) + (size_t)row * HW4;
    float s = 0.f;
    #pragma unroll
    for (int i = 0; i < 3; ++i) {
        float4 v = p[lane + i * 64];
        s += (v.x + v.y) + (v.z + v.w);
    }
    if (lane < 4) {
        float4 v = p[192 + lane];
        s += (v.x + v.y) + (v.z + v.w);
    }
    s = wave_reduce_sum(s);
    if (lane == 0) pooled[row] = s;
}

// ---------------- Kernel 2: logits[b,n] = (1/784) * sum_c pooled[b,c]*W[c,n]
// grid (4, B); block 256 threads; pooled row staged in LDS (broadcast reads).
__global__ void logits_kernel(const float* __restrict__ pooled,
                              const float* __restrict__ W,
                              float* __restrict__ logits) {
    __shared__ float sp[C_DIM];
    int b = blockIdx.y;
    for (int c = threadIdx.x; c < C_DIM; c += 256) sp[c] = pooled[b * C_DIM + c];
    __syncthreads();
    int n = blockIdx.x * 256 + threadIdx.x;
    if (n >= NCLS) return;
    float acc = 0.f;
    #pragma unroll 4
    for (int c = 0; c < C_DIM; ++c) acc += sp[c] * W[c * NCLS + n];
    logits[b * NCLS + n] = acc * (1.0f / (float)HW);
}

// ---------------- Kernel 3: fused softmax + gA ------------------------------
// grid (2, B). Each block: softmax(logits[b,:]) -> q in LDS (computed
// redundantly by both blocks of a b, bitwise-identical to the old two-kernel
// path), then gA[b,c] = (ALPHA/784) * sum_n q[n]*W[c,n] for its 256 c's.
__global__ void smax_gcalc_kernel(const float* __restrict__ logits,
                                  const float* __restrict__ W,
                                  float* __restrict__ gA) {
    __shared__ float sq[NCLS];
    __shared__ float red[4];
    int b = blockIdx.y;
    const float* row = logits + b * NCLS;
    int tid = threadIdx.x, wid = tid >> 6, lane = tid & 63;

    float v[4];
    int cnt = 0;
    float m = -1e30f;
    for (int i = tid; i < NCLS; i += 256) { float x = row[i]; v[cnt++] = x; m = fmaxf(m, x); }
    #pragma unroll
    for (int off = 32; off > 0; off >>= 1) m = fmaxf(m, __shfl_xor(m, off, 64));
    if (lane == 0) red[wid] = m;
    __syncthreads();
    float mm = fmaxf(fmaxf(red[0], red[1]), fmaxf(red[2], red[3]));
    __syncthreads();   // everyone done reading red before reuse

    float s = 0.f;
    cnt = 0;
    for (int i = tid; i < NCLS; i += 256) { float e = expf(v[cnt++] - mm); sq[i] = e; s += e; }
    s = wave_reduce_sum(s);
    if (lane == 0) red[wid] = s;
    __syncthreads();   // also guarantees all sq[] writes visible
    float inv = 1.0f / ((red[0] + red[1]) + (red[2] + red[3]));

    for (int i = tid; i < NCLS; i += 256) sq[i] = sq[i] * inv - (1.0f / (float)NCLS);
    __syncthreads();

    int c = blockIdx.x * 256 + tid;
    const float4* wr = reinterpret_cast<const float4*>(W + c * NCLS);
    float acc = 0.f;
    #pragma unroll 5
    for (int n = 0; n < NCLS / 4; ++n) {
        float4 wv = wr[n];
        acc += sq[4*n] * wv.x + sq[4*n+1] * wv.y + sq[4*n+2] * wv.z + sq[4*n+3] * wv.w;
    }
    gA[b * C_DIM + c] = acc * (ALPHA / (float)HW);
}

// ---------------- Kernel 4: states -> histogram ----------------------------
// One wave per (b,c): mean_hw sigmoid(gA * act), bin, atomicAdd to hist[c][bin].
__global__ void hist_kernel(const float* __restrict__ act,
                            const float* __restrict__ gA,
                            float* __restrict__ hist) {
    int gid  = blockIdx.x * blockDim.x + threadIdx.x;
    int row  = gid >> 6;
    int lane = gid & 63;
    if (row >= NROWS) return;
    float g = gA[row];
    const float4* p = reinterpret_cast<const float4*>(act) + (size_t)row * HW4;
    float s = 0.f;
    #pragma unroll
    for (int i = 0; i < 3; ++i) {
        float4 v = p[lane + i * 64];
        s += 1.0f / (1.0f + expf(-g * v.x));
        s += 1.0f / (1.0f + expf(-g * v.y));
        s += 1.0f / (1.0f + expf(-g * v.z));
        s += 1.0f / (1.0f + expf(-g * v.w));
    }
    if (lane < 4) {
        float4 v = p[192 + lane];
        s += 1.0f / (1.0f + expf(-g * v.x));
        s += 1.0f / (1.0f + expf(-g * v.y));
        s += 1.0f / (1.0f + expf(-g * v.z));
        s += 1.0f / (1.0f + expf(-g * v.w));
    }
    s = wave_reduce_sum(s);
    if (lane == 0) {
        float st = s * (1.0f / (float)HW);
        int idx = (int)floorf(st * (float)MBINS);
        idx = idx < 0 ? 0 : (idx > MBINS - 1 ? MBINS - 1 : idx);
        int c = row & (C_DIM - 1);
        atomicAdd(hist + c * MBINS + idx, 1.0f);
    }
}

extern "C" void kernel_launch(void* const* d_in, const int* in_sizes, int n_in,
                              void* d_out, int out_size, void* d_ws, size_t ws_size,
                              hipStream_t stream) {
    const float* act = (const float*)d_in[0];   // (B,C,H,W) fp32
    const float* W   = (const float*)d_in[1];   // (C,N) fp32
    float* hist      = (float*)d_out;           // (C, MBINS) fp32

    char* ws = (char*)d_ws;
    float* pooled = (float*)ws;                                   // 65536 f
    float* logits = (float*)(ws + (size_t)NROWS * 4);             // 128000 f
    float* gA     = (float*)(ws + (size_t)NROWS * 4
                                + (size_t)B_DIM * NCLS * 4);      // 65536 f

    pool_kernel      <<<NROWS / 4, 256, 0, stream>>>(act, pooled, hist);
    logits_kernel    <<<dim3(4, B_DIM), 256, 0, stream>>>(pooled, W, logits);
    smax_gcalc_kernel<<<dim3(2, B_DIM), 256, 0, stream>>>(logits, W, gA);
    hist_kernel      <<<NROWS / 4, 256, 0, stream>>>(act, gA, hist);
}